// Round 7
// baseline (354.305 us; speedup 1.0000x reference)
//
#include <hip/hip_runtime.h>
#include <cstdint>
#include <cstddef>

// LSTMCreature, seq_len=1, h0=c0=0:
//   per layer: g = x @ Wih(gate rows).T + (bih+bhh); h = sig(go)*tanh(sig(gi)*tanh(gg))
//   f-gate skipped (multiplies c0=0), W_hh unused (h0=0).
// 2-pass hi/lo on W only: x*w ~= xh*wh + xh*wl.
//
// R7: ONE mega-kernel for all 3 layers with per-m-group (8-block, same-XCD)
// device barriers; fcW pre-split in prep and gld16-staged in fc; W planes in ws.

#define NROWS 16384
#define HSZ   256

typedef _Float16 half8  __attribute__((ext_vector_type(8)));
typedef _Float16 half4v __attribute__((ext_vector_type(4)));
typedef float    f32x4  __attribute__((ext_vector_type(4)));

#define VMW(n)  asm volatile("s_waitcnt vmcnt(" #n ")" ::: "memory")
#define LGKM0   asm volatile("s_waitcnt lgkmcnt(0)" ::: "memory")
#define SCHED0  __builtin_amdgcn_sched_barrier(0)
#define BAR()   __builtin_amdgcn_s_barrier()

__device__ __forceinline__ void gld16(const void* g, void* l) {
    __builtin_amdgcn_global_load_lds(
        (const __attribute__((address_space(1))) void*)g,
        (__attribute__((address_space(3))) void*)l, 16, 0, 0);
}

__device__ __forceinline__ float fsig(float x)  { return 1.f / (1.f + __expf(-x)); }
__device__ __forceinline__ float ftanh(float x) { float e = __expf(2.f * x); return 1.f - 2.f / (e + 1.f); }

__device__ __forceinline__ int gate_remap(int row) {   // 768-row id -> 1024-row src (gates i,g,o)
    int g8 = row >> 8;
    int gate = (g8 == 0) ? 0 : g8 + 1;
    return gate * 256 + (row & 255);
}

// ---------------- fused prep: x->fp16; W0/1/2 hi/lo; bsums; fcW hi/lo; zero bars ----------------

#define PS0 524288            /* x chunks: 16384*128/4 */
#define PS1 (PS0 + 24576)     /* W0: 768*32 */
#define PS2 (PS1 + 49152)     /* W1: 768*64 */
#define PS3 (PS2 + 49152)     /* W2 */
#define PS4 (PS3 + 2304)      /* bsums */
#define PS5 (PS4 + 4096)      /* fcW: 64*64 */
#define PS6 (PS5 + 384)       /* barrier counters */

__global__ __launch_bounds__(256)
void prep_all_kernel(const float* __restrict__ x,
                     const float* __restrict__ W0, const float* __restrict__ b0i, const float* __restrict__ b0h,
                     const float* __restrict__ W1, const float* __restrict__ b1i, const float* __restrict__ b1h,
                     const float* __restrict__ W2, const float* __restrict__ b2i, const float* __restrict__ b2h,
                     const float* __restrict__ fcW,
                     _Float16* __restrict__ xh,
                     _Float16* __restrict__ W0h, _Float16* __restrict__ W0l,
                     _Float16* __restrict__ W1h, _Float16* __restrict__ W1l,
                     _Float16* __restrict__ W2h, _Float16* __restrict__ W2l,
                     float* __restrict__ bs0, float* __restrict__ bs1, float* __restrict__ bs2,
                     _Float16* __restrict__ fWh, _Float16* __restrict__ fWl,
                     int* __restrict__ bars)
{
    const int gid = blockIdx.x * 256 + threadIdx.x;
    if (gid < PS0) {
        f32x4 v = ((const f32x4*)x)[gid];
        half4v h;
#pragma unroll
        for (int j = 0; j < 4; ++j) h[j] = (_Float16)v[j];
        ((half4v*)xh)[gid] = h;
    } else if (gid < PS3) {
        const float* W; _Float16 *Wh, *Wl; int j, K;
        if (gid < PS1)      { j = gid - PS0; K = 128; W = W0; Wh = W0h; Wl = W0l; }
        else if (gid < PS2) { j = gid - PS1; K = 256; W = W1; Wh = W1h; Wl = W1l; }
        else                { j = gid - PS2; K = 256; W = W2; Wh = W2h; Wl = W2l; }
        const int K4 = K >> 2;
        int row = j / K4, k4 = j - row * K4;
        int src = gate_remap(row);
        f32x4 v = *(const f32x4*)(W + (size_t)src * K + k4 * 4);
        half4v h, l;
#pragma unroll
        for (int jj = 0; jj < 4; ++jj) { _Float16 hh = (_Float16)v[jj]; h[jj] = hh; l[jj] = (_Float16)(v[jj] - (float)hh); }
        *(half4v*)(Wh + (size_t)row * K + k4 * 4) = h;
        *(half4v*)(Wl + (size_t)row * K + k4 * 4) = l;
    } else if (gid < PS4) {
        int j = gid - PS3;
        int l = (j >= 1536) ? 2 : (j >= 768 ? 1 : 0);
        int r = j - l * 768;
        int src = gate_remap(r);
        const float* bi = (l == 0) ? b0i : (l == 1) ? b1i : b2i;
        const float* bh = (l == 0) ? b0h : (l == 1) ? b1h : b2h;
        float* bs       = (l == 0) ? bs0 : (l == 1) ? bs1 : bs2;
        bs[r] = bi[src] + bh[src];
    } else if (gid < PS5) {
        int j = gid - PS4;            // 0..4095: fcW 64x256 in f32x4 chunks
        f32x4 v = ((const f32x4*)fcW)[j];
        half4v h, l;
#pragma unroll
        for (int jj = 0; jj < 4; ++jj) { _Float16 hh = (_Float16)v[jj]; h[jj] = hh; l[jj] = (_Float16)(v[jj] - (float)hh); }
        ((half4v*)fWh)[j] = h;
        ((half4v*)fWl)[j] = l;
    } else if (gid < PS6) {
        bars[gid - PS5] = 0;
    }
}

// ---------------- group barrier: 8 blocks (same XCD), fence -> signal -> spin ----------------

__device__ __forceinline__ void group_barrier(int* ctr, int t) {
    __threadfence();                  // every thread drains its stores to device scope
    __syncthreads();                  // all threads of the block fenced
    if (t == 0) {
        atomicAdd(ctr, 1);
        while (__hip_atomic_load(ctr, __ATOMIC_RELAXED, __HIP_MEMORY_SCOPE_AGENT) < 8) {
            __builtin_amdgcn_s_sleep(8);
        }
    }
    __syncthreads();
}

// ---------------- layer body (R6-proven structure, as device fn) ----------------
// A LDS: 128 rows x 32k as 64 lines of 128B; line L holds rows (2L,2L+1);
// logical chunk c = ((row&1)<<2)|kc, physical p = c ^ (L&7).
// W LDS: 96 lines of 128B; chunk c = (plane<<2)|kc, p = c ^ (line&7).
// Stage = 2 A + 3 W gld16/thread -> counted vmcnt(5), 2-deep prefetch.

template<int K>
__device__ __forceinline__ void layer_body(
    const _Float16* __restrict__ Ah,
    const _Float16* __restrict__ Wh, const _Float16* __restrict__ Wl,
    const float* __restrict__ bsum, _Float16* __restrict__ Oh,
    _Float16 (*sA)[64 * 64], _Float16 (*sW)[96 * 64],
    int t, int wm, int wn, int lrow, int lkb, int m0, int n0)
{
    constexpr int NT = K / 32;

    f32x4 acc[3][4];
#pragma unroll
    for (int g = 0; g < 3; ++g)
#pragma unroll
        for (int fm = 0; fm < 4; ++fm) acc[g][fm] = (f32x4)0.f;

    auto stage = [&](int bi, int kt) {
        const int k0 = kt * 32;
#pragma unroll
        for (int i = 0; i < 2; ++i) {                 // A: 512 chunks
            int idx = i * 256 + t;
            int line = idx >> 3, p = idx & 7;
            int c = p ^ (line & 7);
            int row = 2 * line + (c >> 2);
            gld16(Ah + (size_t)(m0 + row) * K + k0 + (c & 3) * 8, &sA[bi][idx * 8]);
        }
#pragma unroll
        for (int i = 0; i < 3; ++i) {                 // W: 768 chunks (hi/lo paired)
            int idx = i * 256 + t;
            int line = idx >> 3, p = idx & 7;
            int c = p ^ (line & 7);
            int grow = (line >> 5) * 256 + n0 + (line & 31);
            const _Float16* base = (c & 4) ? Wl : Wh;
            gld16(base + (size_t)grow * K + k0 + (c & 3) * 8, &sW[bi][idx * 8]);
        }
    };

    auto compute = [&](int bi) {
        half8 xh[4];
#pragma unroll
        for (int fm = 0; fm < 4; ++fm) {
            int r = wm * 64 + fm * 16 + lrow;
            int line = r >> 1;
            int c = ((r & 1) << 2) | lkb;
            xh[fm] = *(const half8*)(&sA[bi][line * 64 + ((c ^ (line & 7)) << 3)]);
        }
        half8 wwh[3], wwl[3];
#pragma unroll
        for (int g = 0; g < 3; ++g) {
            int wr = g * 32 + wn * 16 + lrow;
            int rb = wr * 64;
            wwh[g] = *(const half8*)(&sW[bi][rb + ((lkb       ^ (wr & 7)) << 3)]);
            wwl[g] = *(const half8*)(&sW[bi][rb + (((4 | lkb) ^ (wr & 7)) << 3)]);
        }
        __builtin_amdgcn_s_setprio(1);
#pragma unroll
        for (int g = 0; g < 3; ++g)
#pragma unroll
            for (int fm = 0; fm < 4; ++fm) {
                acc[g][fm] = __builtin_amdgcn_mfma_f32_16x16x32_f16(wwh[g], xh[fm], acc[g][fm], 0, 0, 0);
                acc[g][fm] = __builtin_amdgcn_mfma_f32_16x16x32_f16(wwl[g], xh[fm], acc[g][fm], 0, 0, 0);
            }
        __builtin_amdgcn_s_setprio(0);
    };

    stage(0, 0);
    stage(1, 1);                       // 10 loads/thread in flight
    for (int kt = 0; kt < NT; ++kt) {
        if (kt < NT - 1) { VMW(5); }   // tile kt landed; tile kt+1 still in flight
        else             { VMW(0); }
        BAR();
        SCHED0;
        compute(kt & 1);
        LGKM0;
        BAR();
        SCHED0;
        if (kt + 2 < NT) stage(kt & 1, kt + 2);
    }

    // epilogue: n = n0 + wn*16 + lkb*4 + j ; m = m0 + wm*64 + fm*16 + lrow
    const int nbase = n0 + wn * 16 + lkb * 4;
    const f32x4 bI = *(const f32x4*)(bsum + nbase);
    const f32x4 bG = *(const f32x4*)(bsum + 256 + nbase);
    const f32x4 bO = *(const f32x4*)(bsum + 512 + nbase);

#pragma unroll
    for (int fm = 0; fm < 4; ++fm) {
        const int m = m0 + wm * 64 + fm * 16 + lrow;
        half4v oh;
#pragma unroll
        for (int j = 0; j < 4; ++j) {
            float gi = acc[0][fm][j] + bI[j];
            float gg = acc[1][fm][j] + bG[j];
            float go = acc[2][fm][j] + bO[j];
            float c2 = fsig(gi) * ftanh(gg);
            oh[j] = (_Float16)(fsig(go) * ftanh(c2));
        }
        *(half4v*)(Oh + (size_t)m * HSZ + nbase) = oh;
    }
}

// ---------------- mega kernel: 3 layers + per-group barriers ----------------
// bid -> xc=bid&7, q=bid>>3: n0=(q&7)*32, M=xc+8*(q>>3), m0=M*128.
// Group M = the 8 blocks with same M (bid%8==M%8 -> same XCD); its barrier is
// XCD-local. h-rows of group M are read only by group M in the next layer.

__global__ __launch_bounds__(256, 4)
void mega_kernel(const _Float16* __restrict__ xh,
                 const _Float16* __restrict__ W0h, const _Float16* __restrict__ W0l, const float* __restrict__ bs0,
                 const _Float16* __restrict__ W1h, const _Float16* __restrict__ W1l, const float* __restrict__ bs1,
                 const _Float16* __restrict__ W2h, const _Float16* __restrict__ W2l, const float* __restrict__ bs2,
                 _Float16* __restrict__ hA, _Float16* __restrict__ hB,
                 int* __restrict__ bars)
{
    __shared__ __align__(16) _Float16 sA[2][64 * 64];    // 8KB each
    __shared__ __align__(16) _Float16 sW[2][96 * 64];    // 12KB each

    const int t    = threadIdx.x;
    const int lane = t & 63;
    const int wave = t >> 6;
    const int wm   = wave >> 1;
    const int wn   = wave & 1;
    const int lrow = lane & 15;
    const int lkb  = lane >> 4;

    const int bid = blockIdx.x;
    const int xc  = bid & 7, q = bid >> 3;
    const int n0  = (q & 7) * 32;
    const int M   = xc + ((q >> 3) << 3);
    const int m0  = M * 128;

    layer_body<128>(xh, W0h, W0l, bs0, hA, sA, sW, t, wm, wn, lrow, lkb, m0, n0);
    group_barrier(&bars[M], t);
    layer_body<256>(hA, W1h, W1l, bs1, hB, sA, sW, t, wm, wn, lrow, lkb, m0, n0);
    group_barrier(&bars[128 + M], t);
    layer_body<256>(hB, W2h, W2l, bs2, hA, sA, sW, t, wm, wn, lrow, lkb, m0, n0);
}

// ---------------- FC (MFMA, 2-pass, pre-split fcW) + fused tanh-softmax-normalize ----------------

__global__ __launch_bounds__(256)
void fc_softmax_kernel(const _Float16* __restrict__ hhi,
                       const _Float16* __restrict__ fWh, const _Float16* __restrict__ fWl,
                       const float* __restrict__ fcb, float* __restrict__ out)
{
    __shared__ __align__(16) _Float16 sWh[64 * 256];   // 32KB
    __shared__ __align__(16) _Float16 sWl[64 * 256];   // 32KB
    __shared__ __align__(16) _Float16 sH[2][32 * 64];  // 4KB each (row-paired lines)

    const int t    = threadIdx.x;
    const int lane = t & 63;
    const int wave = t >> 6;
    const int ln   = lane & 15;
    const int lkb  = lane >> 4;

    const int bid = blockIdx.x;
    // f/2 == bid (mod 8) -> same XCD as the layer-3 writer of these rows
    const int f   = (((bid & 7) << 1) | ((bid >> 3) & 1)) | ((bid >> 4) << 4);
    const int m0  = f * 64;

    auto stageH = [&](int bi, int kt) {               // 256 chunks: 1/thread
        int idx = t;
        int line = idx >> 3, p = idx & 7;
        int c = p ^ (line & 7);
        int row = 2 * line + (c >> 2);
        gld16(hhi + (size_t)(m0 + row) * 256 + kt * 32 + (c & 3) * 8, &sH[bi][idx * 8]);
    };

    stageH(0, 0);
    stageH(1, 1);

    // stage pre-split fcW planes via gld16: linear dest + inverse-swizzled source
#pragma unroll
    for (int i = 0; i < 16; ++i) {
        int idx = i * 256 + t;          // 0..4095
        int pl  = idx >> 11;            // 0: hi, 1: lo
        int j   = idx & 2047;           // 0..2047
        int row = j >> 5, c = j & 31;
        int cs  = c ^ (row & 7);
        const _Float16* src = (pl ? fWl : fWh) + row * 256 + cs * 8;
        _Float16* dst = (pl ? sWl : sWh) + j * 8;
        gld16(src, dst);
    }

    f32x4 acc[4];
#pragma unroll
    for (int nf = 0; nf < 4; ++nf) acc[nf] = (f32x4)0.f;

    auto computeF = [&](int bi, int kt) {
        const int r = wave * 16 + ln;
        const int line = r >> 1;
        const int hc = ((r & 1) << 2) | lkb;
        half8 ah = *(const half8*)(&sH[bi][line * 64 + ((hc ^ (line & 7)) << 3)]);
        __builtin_amdgcn_s_setprio(1);
#pragma unroll
        for (int nf = 0; nf < 4; ++nf) {
            int wr  = nf * 16 + ln;
            int ch  = kt * 4 + lkb;
            int off = wr * 256 + ((ch ^ (wr & 7)) << 3);
            half8 wwh = *(const half8*)(&sWh[off]);
            half8 wwl = *(const half8*)(&sWl[off]);
            acc[nf] = __builtin_amdgcn_mfma_f32_16x16x32_f16(ah, wwh, acc[nf], 0, 0, 0);
            acc[nf] = __builtin_amdgcn_mfma_f32_16x16x32_f16(ah, wwl, acc[nf], 0, 0, 0);
        }
        __builtin_amdgcn_s_setprio(0);
    };

    __syncthreads();   // one-time: drains all prologue gld16 (vmcnt 0)

    for (int kt = 0; kt < 8; ++kt) {
        if (kt >= 2) {                    // tiles 0,1 covered by syncthreads
            if (kt < 7) { VMW(1); }       // tile kt landed; kt+1 in flight
            else        { VMW(0); }
        }
        BAR();
        SCHED0;
        computeF(kt & 1, kt);
        LGKM0;
        BAR();
        SCHED0;
        if (kt + 2 < 8) stageH(kt & 1, kt + 2);
    }

    // ---- epilogue: bias + tanh-softmax-normalize over n (64) per row ----
    float fb[4];
#pragma unroll
    for (int nf = 0; nf < 4; ++nf) fb[nf] = fcb[nf * 16 + ln];

    float tt[4][4], aa[4][4];
#pragma unroll
    for (int nf = 0; nf < 4; ++nf)
#pragma unroll
        for (int r = 0; r < 4; ++r) {
            float o = acc[nf][r] + fb[nf];
            tt[nf][r] = ftanh(o);
            aa[nf][r] = fabsf(o);
        }

    float mx[4];
#pragma unroll
    for (int r = 0; r < 4; ++r)
        mx[r] = fmaxf(fmaxf(aa[0][r], aa[1][r]), fmaxf(aa[2][r], aa[3][r]));
#pragma unroll
    for (int ofs = 1; ofs < 16; ofs <<= 1)
#pragma unroll
        for (int r = 0; r < 4; ++r) mx[r] = fmaxf(mx[r], __shfl_xor(mx[r], ofs, 64));

    float ee[4][4], Z[4];
#pragma unroll
    for (int r = 0; r < 4; ++r) Z[r] = 0.f;
#pragma unroll
    for (int nf = 0; nf < 4; ++nf)
#pragma unroll
        for (int r = 0; r < 4; ++r) { ee[nf][r] = __expf(aa[nf][r] - mx[r]); Z[r] += ee[nf][r]; }
#pragma unroll
    for (int ofs = 1; ofs < 16; ofs <<= 1)
#pragma unroll
        for (int r = 0; r < 4; ++r) Z[r] += __shfl_xor(Z[r], ofs, 64);

    float w[4][4], S[4];
#pragma unroll
    for (int r = 0; r < 4; ++r) S[r] = 0.f;
#pragma unroll
    for (int nf = 0; nf < 4; ++nf)
#pragma unroll
        for (int r = 0; r < 4; ++r) { w[nf][r] = tt[nf][r] * ee[nf][r] / Z[r]; S[r] += fabsf(w[nf][r]); }
#pragma unroll
    for (int ofs = 1; ofs < 16; ofs <<= 1)
#pragma unroll
        for (int r = 0; r < 4; ++r) S[r] += __shfl_xor(S[r], ofs, 64);

#pragma unroll
    for (int r = 0; r < 4; ++r) {
        const float inv = 1.f / fmaxf(S[r], 1e-12f);
        const int m = m0 + wave * 16 + lkb * 4 + r;
#pragma unroll
        for (int nf = 0; nf < 4; ++nf)
            out[(size_t)m * 64 + nf * 16 + ln] = w[nf][r] * inv;
    }
}

// ---------------- launch ----------------

extern "C" void kernel_launch(void* const* d_in, const int* in_sizes, int n_in,
                              void* d_out, int out_size, void* d_ws, size_t ws_size,
                              hipStream_t stream) {
    const float* x    = (const float*)d_in[0];
    const float* Wih0 = (const float*)d_in[1];
    const float* bih0 = (const float*)d_in[3];
    const float* bhh0 = (const float*)d_in[4];
    const float* Wih1 = (const float*)d_in[5];
    const float* bih1 = (const float*)d_in[7];
    const float* bhh1 = (const float*)d_in[8];
    const float* Wih2 = (const float*)d_in[9];
    const float* bih2 = (const float*)d_in[11];
    const float* bhh2 = (const float*)d_in[12];
    const float* fcW  = (const float*)d_in[13];
    const float* fcb  = (const float*)d_in[14];

    char* ws = (char*)d_ws;
    _Float16* hA  = (_Float16*)(ws);                   // 8 MB
    _Float16* hB  = (_Float16*)(ws + (8u  << 20));     // 8 MB
    _Float16* xh  = (_Float16*)(ws + (16u << 20));     // 4 MB
    _Float16* W0h = (_Float16*)(ws + (20u << 20));     // 192 KB
    _Float16* W0l = (_Float16*)(ws + (21u << 20));
    _Float16* W1h = (_Float16*)(ws + (22u << 20));     // 384 KB
    _Float16* W1l = (_Float16*)(ws + (23u << 20));
    _Float16* W2h = (_Float16*)(ws + (24u << 20));
    _Float16* W2l = (_Float16*)(ws + (25u << 20));
    _Float16* fWh = (_Float16*)(ws + (26u << 20));     // 32 KB
    _Float16* fWl = (_Float16*)(ws + (26u << 20) + 65536);
    float*    bs0 = (float*)(ws + (27u << 20));
    float*    bs1 = (float*)(ws + (27u << 20) + 4096);
    float*    bs2 = (float*)(ws + (27u << 20) + 8192);
    int*      bars = (int*)(ws + (27u << 20) + 16384); // 384 ints
    float*    outp = (float*)d_out;

    dim3 blk(256);

    prep_all_kernel<<<dim3((PS6 + 255) / 256), blk, 0, stream>>>(
        x, Wih0, bih0, bhh0, Wih1, bih1, bhh1, Wih2, bih2, bhh2, fcW,
        xh, W0h, W0l, W1h, W1l, W2h, W2l, bs0, bs1, bs2, fWh, fWl, bars);

    mega_kernel<<<dim3(1024), blk, 0, stream>>>(
        xh, W0h, W0l, bs0, W1h, W1l, bs1, W2h, W2l, bs2, hA, hB, bars);

    fc_softmax_kernel<<<dim3(256), blk, 0, stream>>>(hA, fWh, fWl, fcb, outp);
}

// Round 8
// 68.061 us; speedup vs baseline: 5.2057x; 5.2057x over previous
//
#include <hip/hip_runtime.h>
#include <cstdint>
#include <cstddef>

// LSTMCreature, seq_len=1, h0=c0=0:
//   per layer: g = x @ Wih(gate rows).T + (bih+bhh); h = sig(go)*tanh(sig(gi)*tanh(gg))
//   f-gate skipped (multiplies c0=0), W_hh unused (h0=0).
// R8: SINGLE-pass fp16 (x, W, h all one fp16 plane). Error budget: output
// absmax has sat at 1 output-ulp (2^-12) since R2 through x-lo and h-lo drops;
// W quantization adds ~1.2e-4 rms at gates -> predicted <= 2 ulp, thr = 3.4 ulp.
//   - 12 MFMAs/tile, LDS 28KB/block -> 5 blocks/CU (launch_bounds(256,5))
//   - counted vmcnt (waves 0-2: 4 loads/tile, wave 3: 2), 2-deep prefetch
//   - XCD-local swizzle (bid%8 == M%8) kept from R5/R6

#define NROWS 16384
#define HSZ   256

typedef _Float16 half8  __attribute__((ext_vector_type(8)));
typedef _Float16 half4v __attribute__((ext_vector_type(4)));
typedef float    f32x4  __attribute__((ext_vector_type(4)));

#define VMW(n)  asm volatile("s_waitcnt vmcnt(" #n ")" ::: "memory")
#define LGKM0   asm volatile("s_waitcnt lgkmcnt(0)" ::: "memory")
#define SCHED0  __builtin_amdgcn_sched_barrier(0)
#define BAR()   __builtin_amdgcn_s_barrier()

__device__ __forceinline__ void gld16(const void* g, void* l) {
    __builtin_amdgcn_global_load_lds(
        (const __attribute__((address_space(1))) void*)g,
        (__attribute__((address_space(3))) void*)l, 16, 0, 0);
}

__device__ __forceinline__ float fsig(float x)  { return 1.f / (1.f + __expf(-x)); }
__device__ __forceinline__ float ftanh(float x) { float e = __expf(2.f * x); return 1.f - 2.f / (e + 1.f); }

__device__ __forceinline__ int gate_remap(int row) {   // 768-row id -> 1024-row src (gates i,g,o)
    int g8 = row >> 8;
    int gate = (g8 == 0) ? 0 : g8 + 1;
    return gate * 256 + (row & 255);
}

// ---------------- fused prep: x->fp16; W0/1/2->fp16; bsums; fcW->fp16 ----------------

#define PS0 524288            /* x chunks: 16384*128/4 */
#define PS1 (PS0 + 24576)     /* W0: 768*32 */
#define PS2 (PS1 + 49152)     /* W1: 768*64 */
#define PS3 (PS2 + 49152)     /* W2 */
#define PS4 (PS3 + 2304)      /* bsums */
#define PS5 (PS4 + 4096)      /* fcW: 64*64 */

__global__ __launch_bounds__(256)
void prep_all_kernel(const float* __restrict__ x,
                     const float* __restrict__ W0, const float* __restrict__ b0i, const float* __restrict__ b0h,
                     const float* __restrict__ W1, const float* __restrict__ b1i, const float* __restrict__ b1h,
                     const float* __restrict__ W2, const float* __restrict__ b2i, const float* __restrict__ b2h,
                     const float* __restrict__ fcW,
                     _Float16* __restrict__ xh,
                     _Float16* __restrict__ W0h, _Float16* __restrict__ W1h, _Float16* __restrict__ W2h,
                     float* __restrict__ bs0, float* __restrict__ bs1, float* __restrict__ bs2,
                     _Float16* __restrict__ fWh)
{
    const int gid = blockIdx.x * 256 + threadIdx.x;
    if (gid < PS0) {
        f32x4 v = ((const f32x4*)x)[gid];
        half4v h;
#pragma unroll
        for (int j = 0; j < 4; ++j) h[j] = (_Float16)v[j];
        ((half4v*)xh)[gid] = h;
    } else if (gid < PS3) {
        const float* W; _Float16 *Wh; int j, K;
        if (gid < PS1)      { j = gid - PS0; K = 128; W = W0; Wh = W0h; }
        else if (gid < PS2) { j = gid - PS1; K = 256; W = W1; Wh = W1h; }
        else                { j = gid - PS2; K = 256; W = W2; Wh = W2h; }
        const int K4 = K >> 2;
        int row = j / K4, k4 = j - row * K4;
        int src = gate_remap(row);
        f32x4 v = *(const f32x4*)(W + (size_t)src * K + k4 * 4);
        half4v h;
#pragma unroll
        for (int jj = 0; jj < 4; ++jj) h[jj] = (_Float16)v[jj];
        *(half4v*)(Wh + (size_t)row * K + k4 * 4) = h;
    } else if (gid < PS4) {
        int j = gid - PS3;
        int l = (j >= 1536) ? 2 : (j >= 768 ? 1 : 0);
        int r = j - l * 768;
        int src = gate_remap(r);
        const float* bi = (l == 0) ? b0i : (l == 1) ? b1i : b2i;
        const float* bh = (l == 0) ? b0h : (l == 1) ? b1h : b2h;
        float* bs       = (l == 0) ? bs0 : (l == 1) ? bs1 : bs2;
        bs[r] = bi[src] + bh[src];
    } else if (gid < PS5) {
        int j = gid - PS4;            // 0..4095: fcW 64x256 in f32x4 chunks
        f32x4 v = ((const f32x4*)fcW)[j];
        half4v h;
#pragma unroll
        for (int jj = 0; jj < 4; ++jj) h[jj] = (_Float16)v[jj];
        ((half4v*)fWh)[j] = h;
    }
}

// ---------------- MFMA layer kernel: single-pass fp16 ----------------
// A LDS: 128 rows x 32k as 64 lines of 128B; line L holds rows (2L,2L+1);
// logical chunk c = ((row&1)<<2)|kc, physical p = c ^ (L&7).
// W LDS: 96 rows x 32k as 48 lines of 128B, same pairing/swizzle.
// Stage: A = 2 gld16/thread; W = 384 chunks -> waves 0-2: 2/thread, wave 3: 0.
// Counted vmcnt: waves 0-2 wait vmcnt(4), wave 3 vmcnt(2); 2-deep prefetch.
// XCD: bid -> xc=bid&7, q=bid>>3: n0=(q&7)*32, M=xc+8*(q>>3)  (bid%8 == M%8).

template<int K>
__global__ __launch_bounds__(256, 5)
void lstm_mfma_kernel(const _Float16* __restrict__ Ah,                    // [NROWS][K]
                      const _Float16* __restrict__ Wh,                    // [768][K]
                      const float* __restrict__ bsum,                     // [768]
                      _Float16* __restrict__ Oh)                          // [NROWS][256]
{
    __shared__ __align__(16) _Float16 sA[2][64 * 64];    // 8KB each
    __shared__ __align__(16) _Float16 sW[2][48 * 64];    // 6KB each

    const int t    = threadIdx.x;
    const int lane = t & 63;
    const int wave = t >> 6;
    const int wm   = wave >> 1;
    const int wn   = wave & 1;
    const int lrow = lane & 15;
    const int lkb  = lane >> 4;

    const int bid = blockIdx.x;
    const int xc  = bid & 7, q = bid >> 3;
    const int n0  = (q & 7) * 32;
    const int m0  = (xc + ((q >> 3) << 3)) * 128;
    constexpr int NT = K / 32;

    f32x4 acc[3][4];
#pragma unroll
    for (int g = 0; g < 3; ++g)
#pragma unroll
        for (int fm = 0; fm < 4; ++fm) acc[g][fm] = (f32x4)0.f;

    auto stage = [&](int bi, int kt) {
        const int k0 = kt * 32;
#pragma unroll
        for (int i = 0; i < 2; ++i) {                 // A: 512 chunks
            int idx = i * 256 + t;
            int line = idx >> 3, p = idx & 7;
            int c = p ^ (line & 7);
            int row = 2 * line + (c >> 2);
            gld16(Ah + (size_t)(m0 + row) * K + k0 + (c & 3) * 8, &sA[bi][idx * 8]);
        }
        if (t < 192) {                                // W: 384 chunks (waves 0-2)
#pragma unroll
            for (int i = 0; i < 2; ++i) {
                int idx = i * 192 + t;
                int line = idx >> 3, p = idx & 7;     // line 0..47
                int c = p ^ (line & 7);
                int row = 2 * line + (c >> 2);        // 0..95
                int grow = (row >> 5) * 256 + n0 + (row & 31);
                gld16(Wh + (size_t)grow * K + k0 + (c & 3) * 8, &sW[bi][idx * 8]);
            }
        }
    };

    auto compute = [&](int bi) {
        half8 xh[4];
#pragma unroll
        for (int fm = 0; fm < 4; ++fm) {
            int r = wm * 64 + fm * 16 + lrow;
            int line = r >> 1;
            int c = ((r & 1) << 2) | lkb;
            xh[fm] = *(const half8*)(&sA[bi][line * 64 + ((c ^ (line & 7)) << 3)]);
        }
        half8 ww[3];
#pragma unroll
        for (int g = 0; g < 3; ++g) {
            int wr = g * 32 + wn * 16 + lrow;
            int line = wr >> 1;
            int c = ((wr & 1) << 2) | lkb;
            ww[g] = *(const half8*)(&sW[bi][line * 64 + ((c ^ (line & 7)) << 3)]);
        }
        __builtin_amdgcn_s_setprio(1);
#pragma unroll
        for (int g = 0; g < 3; ++g)
#pragma unroll
            for (int fm = 0; fm < 4; ++fm)
                acc[g][fm] = __builtin_amdgcn_mfma_f32_16x16x32_f16(ww[g], xh[fm], acc[g][fm], 0, 0, 0);
        __builtin_amdgcn_s_setprio(0);
    };

    stage(0, 0);
    stage(1, 1);                       // 2 tiles in flight
    for (int kt = 0; kt < NT; ++kt) {
        if (kt < NT - 1) {             // tile kt landed; kt+1 still in flight
            if (wave < 3) { VMW(4); } else { VMW(2); }
        } else {
            VMW(0);
        }
        BAR();
        SCHED0;
        compute(kt & 1);
        LGKM0;
        BAR();
        SCHED0;
        if (kt + 2 < NT) stage(kt & 1, kt + 2);
    }

    // epilogue: n = n0 + wn*16 + lkb*4 + j ; m = m0 + wm*64 + fm*16 + lrow
    const int nbase = n0 + wn * 16 + lkb * 4;
    const f32x4 bI = *(const f32x4*)(bsum + nbase);
    const f32x4 bG = *(const f32x4*)(bsum + 256 + nbase);
    const f32x4 bO = *(const f32x4*)(bsum + 512 + nbase);

#pragma unroll
    for (int fm = 0; fm < 4; ++fm) {
        const int m = m0 + wm * 64 + fm * 16 + lrow;
        half4v oh;
#pragma unroll
        for (int j = 0; j < 4; ++j) {
            float gi = acc[0][fm][j] + bI[j];
            float gg = acc[1][fm][j] + bG[j];
            float go = acc[2][fm][j] + bO[j];
            float c2 = fsig(gi) * ftanh(gg);
            oh[j] = (_Float16)(fsig(go) * ftanh(c2));
        }
        *(half4v*)(Oh + (size_t)m * HSZ + nbase) = oh;
    }
}

// ---------------- FC (MFMA, single-pass, pre-split fcW) + tanh-softmax-normalize ----------------

__global__ __launch_bounds__(256)
void fc_softmax_kernel(const _Float16* __restrict__ hhi,
                       const _Float16* __restrict__ fWh,
                       const float* __restrict__ fcb, float* __restrict__ out)
{
    __shared__ __align__(16) _Float16 sWh[64 * 256];   // 32KB
    __shared__ __align__(16) _Float16 sH[2][32 * 64];  // 4KB each (row-paired lines)

    const int t    = threadIdx.x;
    const int lane = t & 63;
    const int wave = t >> 6;
    const int ln   = lane & 15;
    const int lkb  = lane >> 4;

    const int bid = blockIdx.x;
    // f/2 == bid (mod 8) -> same XCD as the layer-3 writer of these rows
    const int f   = (((bid & 7) << 1) | ((bid >> 3) & 1)) | ((bid >> 4) << 4);
    const int m0  = f * 64;

    auto stageH = [&](int bi, int kt) {               // 256 chunks: 1/thread
        int idx = t;
        int line = idx >> 3, p = idx & 7;
        int c = p ^ (line & 7);
        int row = 2 * line + (c >> 2);
        gld16(hhi + (size_t)(m0 + row) * 256 + kt * 32 + (c & 3) * 8, &sH[bi][idx * 8]);
    };

    stageH(0, 0);
    stageH(1, 1);

    // stage pre-split fcW plane via gld16: linear dest + inverse-swizzled source
#pragma unroll
    for (int i = 0; i < 8; ++i) {
        int j = i * 256 + t;            // 0..2047
        int row = j >> 5, c = j & 31;
        int cs  = c ^ (row & 7);
        gld16(fWh + row * 256 + cs * 8, sWh + j * 8);
    }

    f32x4 acc[4];
#pragma unroll
    for (int nf = 0; nf < 4; ++nf) acc[nf] = (f32x4)0.f;

    auto computeF = [&](int bi, int kt) {
        const int r = wave * 16 + ln;
        const int line = r >> 1;
        const int hc = ((r & 1) << 2) | lkb;
        half8 ah = *(const half8*)(&sH[bi][line * 64 + ((hc ^ (line & 7)) << 3)]);
        __builtin_amdgcn_s_setprio(1);
#pragma unroll
        for (int nf = 0; nf < 4; ++nf) {
            int wr  = nf * 16 + ln;
            int ch  = kt * 4 + lkb;
            int off = wr * 256 + ((ch ^ (wr & 7)) << 3);
            half8 wwh = *(const half8*)(&sWh[off]);
            acc[nf] = __builtin_amdgcn_mfma_f32_16x16x32_f16(ah, wwh, acc[nf], 0, 0, 0);
        }
        __builtin_amdgcn_s_setprio(0);
    };

    __syncthreads();   // one-time: drains all prologue gld16 (vmcnt 0)

    for (int kt = 0; kt < 8; ++kt) {
        if (kt >= 2) {                    // tiles 0,1 covered by syncthreads
            if (kt < 7) { VMW(1); }       // tile kt landed; kt+1 in flight
            else        { VMW(0); }
        }
        BAR();
        SCHED0;
        computeF(kt & 1, kt);
        LGKM0;
        BAR();
        SCHED0;
        if (kt + 2 < 8) stageH(kt & 1, kt + 2);
    }

    // ---- epilogue: bias + tanh-softmax-normalize over n (64) per row ----
    float fb[4];
#pragma unroll
    for (int nf = 0; nf < 4; ++nf) fb[nf] = fcb[nf * 16 + ln];

    float tt[4][4], aa[4][4];
#pragma unroll
    for (int nf = 0; nf < 4; ++nf)
#pragma unroll
        for (int r = 0; r < 4; ++r) {
            float o = acc[nf][r] + fb[nf];
            tt[nf][r] = ftanh(o);
            aa[nf][r] = fabsf(o);
        }

    float mx[4];
#pragma unroll
    for (int r = 0; r < 4; ++r)
        mx[r] = fmaxf(fmaxf(aa[0][r], aa[1][r]), fmaxf(aa[2][r], aa[3][r]));
#pragma unroll
    for (int ofs = 1; ofs < 16; ofs <<= 1)
#pragma unroll
        for (int r = 0; r < 4; ++r) mx[r] = fmaxf(mx[r], __shfl_xor(mx[r], ofs, 64));

    float ee[4][4], Z[4];
#pragma unroll
    for (int r = 0; r < 4; ++r) Z[r] = 0.f;
#pragma unroll
    for (int nf = 0; nf < 4; ++nf)
#pragma unroll
        for (int r = 0; r < 4; ++r) { ee[nf][r] = __expf(aa[nf][r] - mx[r]); Z[r] += ee[nf][r]; }
#pragma unroll
    for (int ofs = 1; ofs < 16; ofs <<= 1)
#pragma unroll
        for (int r = 0; r < 4; ++r) Z[r] += __shfl_xor(Z[r], ofs, 64);

    float w[4][4], S[4];
#pragma unroll
    for (int r = 0; r < 4; ++r) S[r] = 0.f;
#pragma unroll
    for (int nf = 0; nf < 4; ++nf)
#pragma unroll
        for (int r = 0; r < 4; ++r) { w[nf][r] = tt[nf][r] * ee[nf][r] / Z[r]; S[r] += fabsf(w[nf][r]); }
#pragma unroll
    for (int ofs = 1; ofs < 16; ofs <<= 1)
#pragma unroll
        for (int r = 0; r < 4; ++r) S[r] += __shfl_xor(S[r], ofs, 64);

#pragma unroll
    for (int r = 0; r < 4; ++r) {
        const float inv = 1.f / fmaxf(S[r], 1e-12f);
        const int m = m0 + wave * 16 + lkb * 4 + r;
#pragma unroll
        for (int nf = 0; nf < 4; ++nf)
            out[(size_t)m * 64 + nf * 16 + ln] = w[nf][r] * inv;
    }
}

// ---------------- launch ----------------

extern "C" void kernel_launch(void* const* d_in, const int* in_sizes, int n_in,
                              void* d_out, int out_size, void* d_ws, size_t ws_size,
                              hipStream_t stream) {
    const float* x    = (const float*)d_in[0];
    const float* Wih0 = (const float*)d_in[1];
    const float* bih0 = (const float*)d_in[3];
    const float* bhh0 = (const float*)d_in[4];
    const float* Wih1 = (const float*)d_in[5];
    const float* bih1 = (const float*)d_in[7];
    const float* bhh1 = (const float*)d_in[8];
    const float* Wih2 = (const float*)d_in[9];
    const float* bih2 = (const float*)d_in[11];
    const float* bhh2 = (const float*)d_in[12];
    const float* fcW  = (const float*)d_in[13];
    const float* fcb  = (const float*)d_in[14];

    char* ws = (char*)d_ws;
    _Float16* hA  = (_Float16*)(ws);                   // 8 MB
    _Float16* hB  = (_Float16*)(ws + (8u  << 20));     // 8 MB
    _Float16* xh  = (_Float16*)(ws + (16u << 20));     // 4 MB
    _Float16* W0h = (_Float16*)(ws + (20u << 20));     // 192 KB
    _Float16* W1h = (_Float16*)(ws + (21u << 20));     // 384 KB
    _Float16* W2h = (_Float16*)(ws + (22u << 20));     // 384 KB
    _Float16* fWh = (_Float16*)(ws + (23u << 20));     // 32 KB
    float*    bs0 = (float*)(ws + (24u << 20));
    float*    bs1 = (float*)(ws + (24u << 20) + 4096);
    float*    bs2 = (float*)(ws + (24u << 20) + 8192);
    float*    outp = (float*)d_out;

    dim3 blk(256);

    prep_all_kernel<<<dim3((PS5 + 255) / 256), blk, 0, stream>>>(
        x, Wih0, bih0, bhh0, Wih1, bih1, bhh1, Wih2, bih2, bhh2, fcW,
        xh, W0h, W1h, W2h, bs0, bs1, bs2, fWh);

    lstm_mfma_kernel<128><<<dim3(1024), blk, 0, stream>>>(xh, W0h, bs0, hA);
    lstm_mfma_kernel<256><<<dim3(1024), blk, 0, stream>>>(hA, W1h, bs1, hB);
    lstm_mfma_kernel<256><<<dim3(1024), blk, 0, stream>>>(hB, W2h, bs2, hA);

    fc_softmax_kernel<<<dim3(256), blk, 0, stream>>>(hA, fWh, fcb, outp);
}